// Round 3
// baseline (13866.702 us; speedup 1.0000x reference)
//
#include <hip/hip_runtime.h>
#include <cstdint>
#include <cstddef>

#define IN_DIM 256
#define HID    512
#define TSTEPS 8
#define ROWS   16      // batch rows per block
#define RPT    8       // rows per thread
#define NTHR   512
#define KC4    96      // OpenBLAS sgemm kc=384 panel boundary, in float4 units

// Sequential-k fp32 FMA chain over [i4begin, i4end), single accumulator per
// output element -- replicates the BLAS GEBP microkernel's rounding order.
// Spike/obs tile in LDS (wave-uniform broadcast reads), weight rows from L2.
template<int PITCH4>
__device__ __forceinline__ void gemm_f32(const float* __restrict__ sl, int rbase,
                                         const float4* __restrict__ wra,
                                         const float4* __restrict__ wrb,
                                         int i4begin, int i4end,
                                         float a0[RPT], float a1[RPT]) {
  const float4* slv = reinterpret_cast<const float4*>(sl);
  for (int i4 = i4begin; i4 < i4end; ++i4) {
    float4 wa = wra[i4];
    float4 wb = wrb[i4];
#pragma unroll
    for (int r = 0; r < RPT; ++r) {
      float4 s = slv[(rbase + r) * PITCH4 + i4];
      // ascending-k order: x, y, z, w (innermost fma first)
      a0[r] = fmaf(s.w, wa.w, fmaf(s.z, wa.z, fmaf(s.y, wa.y, fmaf(s.x, wa.x, a0[r]))));
      a1[r] = fmaf(s.w, wb.w, fmaf(s.z, wb.z, fmaf(s.y, wb.y, fmaf(s.x, wb.x, a1[r]))));
    }
  }
}

__launch_bounds__(NTHR, 2)
__global__ void snn_net(const float* __restrict__ obs,
                        const float* __restrict__ pW1, const float* __restrict__ pb1_,
                        const float* __restrict__ pW2, const float* __restrict__ pb2_,
                        const float* __restrict__ pW3, const float* __restrict__ pb3_,
                        const float* __restrict__ paw, const float* __restrict__ pab,
                        const float* __restrict__ vW1, const float* __restrict__ vb1_,
                        const float* __restrict__ vW2, const float* __restrict__ vb2_,
                        const float* __restrict__ vW3, const float* __restrict__ vb3_,
                        const float* __restrict__ vhw, const float* __restrict__ vhb,
                        const float* __restrict__ log_std,
                        float* __restrict__ out, int B) {
  const int is_value = blockIdx.y;
  const float* W1 = is_value ? vW1 : pW1;  const float* b1 = is_value ? vb1_ : pb1_;
  const float* W2 = is_value ? vW2 : pW2;  const float* b2 = is_value ? vb2_ : pb2_;
  const float* W3 = is_value ? vW3 : pW3;  const float* b3 = is_value ? vb3_ : pb3_;
  const float* Wh = is_value ? vhw : paw;  const float* bh = is_value ? vhb : pab;

  __shared__ float sl[ROWS * HID];  // 32 KB: obs tile then spike tile
  const int tid = threadIdx.x;
  const int r0 = blockIdx.x * ROWS;
  const int j1 = tid & 255, j2 = j1 + 256;
  const int rbase = (tid >> 8) * RPT;   // 0 or 8

  // ---- stage obs tile
  for (int e = tid; e < ROWS * IN_DIM; e += NTHR)
    sl[e] = obs[(size_t)r0 * IN_DIM + e];
  __syncthreads();

  // ---- layer-1 currents: K=256 -> single BLAS panel; bias added AFTER sum
  float c1a[RPT], c1b[RPT];
  {
    float Sa[RPT], Sb[RPT];
#pragma unroll
    for (int r = 0; r < RPT; ++r) { Sa[r] = 0.f; Sb[r] = 0.f; }
    gemm_f32<IN_DIM / 4>(sl, rbase,
        reinterpret_cast<const float4*>(W1 + (size_t)j1 * IN_DIM),
        reinterpret_cast<const float4*>(W1 + (size_t)j2 * IN_DIM),
        0, IN_DIM / 4, Sa, Sb);
    const float ba = b1[j1], bb = b1[j2];
#pragma unroll
    for (int r = 0; r < RPT; ++r) {
      c1a[r] = __fadd_rn(Sa[r], ba);
      c1b[r] = __fadd_rn(Sb[r], bb);
    }
  }
  __syncthreads();  // obs tile dead; sl becomes spike tile

  // ---- fp32 state (numpy-order arithmetic throughout)
  float m1a[RPT], m1b[RPT], m2a[RPT], m2b[RPT], m3a[RPT], m3b[RPT];
  float sca[RPT], scb[RPT];
#pragma unroll
  for (int r = 0; r < RPT; ++r) {
    m1a[r] = 0.f; m1b[r] = 0.f; m2a[r] = 0.f; m2b[r] = 0.f;
    m3a[r] = 0.f; m3b[r] = 0.f; sca[r] = 0.f; scb[r] = 0.f;
  }

  const float4* w2a = reinterpret_cast<const float4*>(W2 + (size_t)j1 * HID);
  const float4* w2b = reinterpret_cast<const float4*>(W2 + (size_t)j2 * HID);
  const float4* w3a = reinterpret_cast<const float4*>(W3 + (size_t)j1 * HID);
  const float4* w3b = reinterpret_cast<const float4*>(W3 + (size_t)j2 * HID);
  const float bias2a = b2[j1], bias2b = b2[j2];
  const float bias3a = b3[j1], bias3b = b3[j2];

  for (int t = 0; t < TSTEPS; ++t) {
    // LIF layer 1: m = RN(RN(0.95*m) + cur)  (no fma -- numpy does mul then add)
#pragma unroll
    for (int r = 0; r < RPT; ++r) {
      m1a[r] = __fadd_rn(__fmul_rn(0.95f, m1a[r]), c1a[r]);
      float sa = (m1a[r] > 1.0f) ? 1.0f : 0.0f;
      m1a[r] = __fsub_rn(m1a[r], sa);
      sl[(rbase + r) * HID + j1] = sa;
      m1b[r] = __fadd_rn(__fmul_rn(0.95f, m1b[r]), c1b[r]);
      float sb = (m1b[r] > 1.0f) ? 1.0f : 0.0f;
      m1b[r] = __fsub_rn(m1b[r], sb);
      sl[(rbase + r) * HID + j2] = sb;
    }
    __syncthreads();

    // layer 2: K=512 -> two BLAS panels (kc=384), then RN(S0+S1), then +bias
    float S0a[RPT], S0b[RPT], S1a[RPT], S1b[RPT];
#pragma unroll
    for (int r = 0; r < RPT; ++r) { S0a[r] = 0.f; S0b[r] = 0.f; S1a[r] = 0.f; S1b[r] = 0.f; }
    gemm_f32<HID / 4>(sl, rbase, w2a, w2b, 0, KC4, S0a, S0b);
    gemm_f32<HID / 4>(sl, rbase, w2a, w2b, KC4, HID / 4, S1a, S1b);
    __syncthreads();  // s1 reads done before overwrite
#pragma unroll
    for (int r = 0; r < RPT; ++r) {
      float cura = __fadd_rn(__fadd_rn(S0a[r], S1a[r]), bias2a);
      float curb = __fadd_rn(__fadd_rn(S0b[r], S1b[r]), bias2b);
      m2a[r] = __fadd_rn(__fmul_rn(0.95f, m2a[r]), cura);
      float sa = (m2a[r] > 1.0f) ? 1.0f : 0.0f;
      m2a[r] = __fsub_rn(m2a[r], sa);
      sl[(rbase + r) * HID + j1] = sa;
      m2b[r] = __fadd_rn(__fmul_rn(0.95f, m2b[r]), curb);
      float sb = (m2b[r] > 1.0f) ? 1.0f : 0.0f;
      m2b[r] = __fsub_rn(m2b[r], sb);
      sl[(rbase + r) * HID + j2] = sb;
    }
    __syncthreads();

    // layer 3: same two-panel structure; accumulate spike counts
#pragma unroll
    for (int r = 0; r < RPT; ++r) { S0a[r] = 0.f; S0b[r] = 0.f; S1a[r] = 0.f; S1b[r] = 0.f; }
    gemm_f32<HID / 4>(sl, rbase, w3a, w3b, 0, KC4, S0a, S0b);
    gemm_f32<HID / 4>(sl, rbase, w3a, w3b, KC4, HID / 4, S1a, S1b);
    __syncthreads();  // s2 reads done before next step overwrites
#pragma unroll
    for (int r = 0; r < RPT; ++r) {
      float cura = __fadd_rn(__fadd_rn(S0a[r], S1a[r]), bias3a);
      float curb = __fadd_rn(__fadd_rn(S0b[r], S1b[r]), bias3b);
      m3a[r] = __fadd_rn(__fmul_rn(0.95f, m3a[r]), cura);
      float sa = (m3a[r] > 1.0f) ? 1.0f : 0.0f;
      m3a[r] = __fsub_rn(m3a[r], sa);
      sca[r] = __fadd_rn(sca[r], sa);   // integer counts: exact
      m3b[r] = __fadd_rn(__fmul_rn(0.95f, m3b[r]), curb);
      float sb = (m3b[r] > 1.0f) ? 1.0f : 0.0f;
      m3b[r] = __fsub_rn(m3b[r], sb);
      scb[r] = __fadd_rn(scb[r], sb);
    }
  }

  // ---- mean spikes (k/8 exact) into LDS
#pragma unroll
  for (int r = 0; r < RPT; ++r) {
    sl[(rbase + r) * HID + j1] = sca[r] * 0.125f;
    sl[(rbase + r) * HID + j2] = scb[r] * 0.125f;
  }
  __syncthreads();

  // ---- heads: same BLAS panel structure (sub-flip precision anyway)
  if (is_value == 0) {
    if (tid < ROWS * 6) {
      int r = tid / 6, k = tid % 6;
      const float* wr = Wh + (size_t)k * HID;
      float S0 = 0.f, S1 = 0.f;
      for (int i = 0; i < 4 * KC4; ++i)   S0 = fmaf(sl[r * HID + i], wr[i], S0);
      for (int i = 4 * KC4; i < HID; ++i) S1 = fmaf(sl[r * HID + i], wr[i], S1);
      out[(size_t)(r0 + r) * 6 + k] = __fadd_rn(__fadd_rn(S0, S1), bh[k]);
      out[(size_t)B * 6 + (size_t)(r0 + r) * 6 + k] = log_std[k];
    }
  } else {
    if (tid < ROWS) {
      int r = tid;
      float S0 = 0.f, S1 = 0.f;
      for (int i = 0; i < 4 * KC4; ++i)   S0 = fmaf(sl[r * HID + i], Wh[i], S0);
      for (int i = 4 * KC4; i < HID; ++i) S1 = fmaf(sl[r * HID + i], Wh[i], S1);
      out[(size_t)B * 12 + (size_t)(r0 + r)] = __fadd_rn(__fadd_rn(S0, S1), bh[0]);
    }
  }
}

extern "C" void kernel_launch(void* const* d_in, const int* in_sizes, int n_in,
                              void* d_out, int out_size, void* d_ws, size_t ws_size,
                              hipStream_t stream) {
  const float* obs = (const float*)d_in[0];
  const float* pw1 = (const float*)d_in[1];  const float* pb1 = (const float*)d_in[2];
  const float* pw2 = (const float*)d_in[3];  const float* pb2 = (const float*)d_in[4];
  const float* pw3 = (const float*)d_in[5];  const float* pb3 = (const float*)d_in[6];
  const float* aw  = (const float*)d_in[7];  const float* ab  = (const float*)d_in[8];
  const float* vw1 = (const float*)d_in[9];  const float* vb1 = (const float*)d_in[10];
  const float* vw2 = (const float*)d_in[11]; const float* vb2 = (const float*)d_in[12];
  const float* vw3 = (const float*)d_in[13]; const float* vb3 = (const float*)d_in[14];
  const float* hw  = (const float*)d_in[15]; const float* hb  = (const float*)d_in[16];
  const float* lsd = (const float*)d_in[17];
  float* out = (float*)d_out;

  const int B  = in_sizes[0] / IN_DIM;
  dim3 grid(B / ROWS, 2);

  snn_net<<<grid, NTHR, 0, stream>>>(obs,
      pw1, pb1, pw2, pb2, pw3, pb3, aw, ab,
      vw1, vb1, vw2, vb2, vw3, vb3, hw, hb,
      lsd, out, B);
}

// Round 4
// 4872.792 us; speedup vs baseline: 2.8457x; 2.8457x over previous
//
#include <hip/hip_runtime.h>
#include <cstdint>
#include <cstddef>

#define IN_DIM 256
#define HID    512
#define TSTEPS 8
#define ROWS   16      // batch rows per block
#define RPT    8       // rows per thread
#define NTHR   512
#define KC4    96      // OpenBLAS sgemm kc=384 panel boundary, in float4 units

// ---------------- weight transpose: in[R][C] -> outT[C][R] ----------------
__global__ void wtrans(const float* __restrict__ in, float* __restrict__ outT,
                       int R, int C) {
  __shared__ float tile[32][33];
  const int c0 = blockIdx.x * 32, r0 = blockIdx.y * 32;
  const int tx = threadIdx.x & 31, ty = threadIdx.x >> 5;   // 32x8
#pragma unroll
  for (int i = 0; i < 32; i += 8)
    tile[ty + i][tx] = in[(size_t)(r0 + ty + i) * C + (c0 + tx)];
  __syncthreads();
#pragma unroll
  for (int i = 0; i < 32; i += 8)
    outT[(size_t)(c0 + ty + i) * R + (r0 + tx)] = tile[tx][ty + i];
}

// ---------------- fast path: transposed-weight GEMM core ----------------
// Ascending-k fp32 fma chain (BLAS GEBP order, bit-identical to round-3 kernel).
// Weights from WT[k][j]: per-lane j consecutive -> fully coalesced scalar loads.
// Spike/obs tile reads are wave-uniform broadcast ds_read_b128 (conflict-free).
template<int PITCH4>
__device__ __forceinline__ void gemm_t(const float* __restrict__ sl, int rbase,
                                       const float* __restrict__ wt_j,  // WT + j1
                                       int i4begin, int i4end,
                                       float a0[RPT], float a1[RPT]) {
  const float4* slv = reinterpret_cast<const float4*>(sl);
  const float* wp = wt_j + (size_t)i4begin * 4 * HID;
  for (int i4 = i4begin; i4 < i4end; ++i4) {
    float wa0 = wp[0 * HID],       wa1 = wp[1 * HID];
    float wa2 = wp[2 * HID],       wa3 = wp[3 * HID];
    float wb0 = wp[0 * HID + 256], wb1 = wp[1 * HID + 256];
    float wb2 = wp[2 * HID + 256], wb3 = wp[3 * HID + 256];
#pragma unroll
    for (int r = 0; r < RPT; ++r) {
      float4 s = slv[(rbase + r) * PITCH4 + i4];
      a0[r] = fmaf(s.w, wa3, fmaf(s.z, wa2, fmaf(s.y, wa1, fmaf(s.x, wa0, a0[r]))));
      a1[r] = fmaf(s.w, wb3, fmaf(s.z, wb2, fmaf(s.y, wb1, fmaf(s.x, wb0, a1[r]))));
    }
    wp += 4 * HID;
  }
}

__launch_bounds__(NTHR, 4)
__global__ void snn_net(const float* __restrict__ obs,
                        const float* __restrict__ pW1T, const float* __restrict__ pb1_,
                        const float* __restrict__ pW2T, const float* __restrict__ pb2_,
                        const float* __restrict__ pW3T, const float* __restrict__ pb3_,
                        const float* __restrict__ paw, const float* __restrict__ pab,
                        const float* __restrict__ vW1T, const float* __restrict__ vb1_,
                        const float* __restrict__ vW2T, const float* __restrict__ vb2_,
                        const float* __restrict__ vW3T, const float* __restrict__ vb3_,
                        const float* __restrict__ vhw, const float* __restrict__ vhb,
                        const float* __restrict__ log_std,
                        float* __restrict__ out, int B) {
  const int is_value = blockIdx.y;
  const float* W1T = is_value ? vW1T : pW1T;  const float* b1 = is_value ? vb1_ : pb1_;
  const float* W2T = is_value ? vW2T : pW2T;  const float* b2 = is_value ? vb2_ : pb2_;
  const float* W3T = is_value ? vW3T : pW3T;  const float* b3 = is_value ? vb3_ : pb3_;
  const float* Wh  = is_value ? vhw  : paw;   const float* bh = is_value ? vhb : pab;

  __shared__ float sl[ROWS * HID];  // 32 KB: obs tile then spike tile
  const int tid = threadIdx.x;
  const int r0 = blockIdx.x * ROWS;
  const int j1 = tid & 255;
  const int rbase = (tid >> 8) * RPT;   // 0 or 8

  // ---- stage obs tile
  for (int e = tid; e < ROWS * IN_DIM; e += NTHR)
    sl[e] = obs[(size_t)r0 * IN_DIM + e];
  __syncthreads();

  // ---- layer-1 currents: K=256 single panel; bias added AFTER sum
  float c1a[RPT], c1b[RPT];
  {
    float Sa[RPT], Sb[RPT];
#pragma unroll
    for (int r = 0; r < RPT; ++r) { Sa[r] = 0.f; Sb[r] = 0.f; }
    gemm_t<IN_DIM / 4>(sl, rbase, W1T + j1, 0, IN_DIM / 4, Sa, Sb);
    const float ba = b1[j1], bb = b1[j1 + 256];
#pragma unroll
    for (int r = 0; r < RPT; ++r) {
      c1a[r] = __fadd_rn(Sa[r], ba);
      c1b[r] = __fadd_rn(Sb[r], bb);
    }
  }
  __syncthreads();  // obs tile dead; sl becomes spike tile

  // ---- fp32 membrane state; layer-3 spike counts packed 4b x 8 per u32
  float m1a[RPT], m1b[RPT], m2a[RPT], m2b[RPT], m3a[RPT], m3b[RPT];
  unsigned cnt_a = 0u, cnt_b = 0u;
#pragma unroll
  for (int r = 0; r < RPT; ++r) {
    m1a[r] = 0.f; m1b[r] = 0.f; m2a[r] = 0.f; m2b[r] = 0.f;
    m3a[r] = 0.f; m3b[r] = 0.f;
  }

  const float bias2a = b2[j1], bias2b = b2[j1 + 256];
  const float bias3a = b3[j1], bias3b = b3[j1 + 256];

  for (int t = 0; t < TSTEPS; ++t) {
    // LIF layer 1: m = RN(RN(0.95*m) + cur)  (numpy: mul then add, no fma)
#pragma unroll
    for (int r = 0; r < RPT; ++r) {
      m1a[r] = __fadd_rn(__fmul_rn(0.95f, m1a[r]), c1a[r]);
      float sa = (m1a[r] > 1.0f) ? 1.0f : 0.0f;
      m1a[r] = __fsub_rn(m1a[r], sa);
      sl[(rbase + r) * HID + j1] = sa;
      m1b[r] = __fadd_rn(__fmul_rn(0.95f, m1b[r]), c1b[r]);
      float sb = (m1b[r] > 1.0f) ? 1.0f : 0.0f;
      m1b[r] = __fsub_rn(m1b[r], sb);
      sl[(rbase + r) * HID + j1 + 256] = sb;
    }
    __syncthreads();

    // layer 2: two BLAS panels (kc=384), RN(S0+S1), then +bias
    float S0a[RPT], S0b[RPT], S1a[RPT], S1b[RPT];
#pragma unroll
    for (int r = 0; r < RPT; ++r) { S0a[r] = 0.f; S0b[r] = 0.f; S1a[r] = 0.f; S1b[r] = 0.f; }
    gemm_t<HID / 4>(sl, rbase, W2T + j1, 0, KC4, S0a, S0b);
    gemm_t<HID / 4>(sl, rbase, W2T + j1, KC4, HID / 4, S1a, S1b);
    __syncthreads();  // s1 reads done before overwrite
#pragma unroll
    for (int r = 0; r < RPT; ++r) {
      float cura = __fadd_rn(__fadd_rn(S0a[r], S1a[r]), bias2a);
      float curb = __fadd_rn(__fadd_rn(S0b[r], S1b[r]), bias2b);
      m2a[r] = __fadd_rn(__fmul_rn(0.95f, m2a[r]), cura);
      float sa = (m2a[r] > 1.0f) ? 1.0f : 0.0f;
      m2a[r] = __fsub_rn(m2a[r], sa);
      sl[(rbase + r) * HID + j1] = sa;
      m2b[r] = __fadd_rn(__fmul_rn(0.95f, m2b[r]), curb);
      float sb = (m2b[r] > 1.0f) ? 1.0f : 0.0f;
      m2b[r] = __fsub_rn(m2b[r], sb);
      sl[(rbase + r) * HID + j1 + 256] = sb;
    }
    __syncthreads();

    // layer 3: same two-panel structure; packed spike counts
#pragma unroll
    for (int r = 0; r < RPT; ++r) { S0a[r] = 0.f; S0b[r] = 0.f; S1a[r] = 0.f; S1b[r] = 0.f; }
    gemm_t<HID / 4>(sl, rbase, W3T + j1, 0, KC4, S0a, S0b);
    gemm_t<HID / 4>(sl, rbase, W3T + j1, KC4, HID / 4, S1a, S1b);
    __syncthreads();  // s2 reads done before next step overwrites
#pragma unroll
    for (int r = 0; r < RPT; ++r) {
      float cura = __fadd_rn(__fadd_rn(S0a[r], S1a[r]), bias3a);
      float curb = __fadd_rn(__fadd_rn(S0b[r], S1b[r]), bias3b);
      m3a[r] = __fadd_rn(__fmul_rn(0.95f, m3a[r]), cura);
      bool fa = m3a[r] > 1.0f;
      m3a[r] = __fsub_rn(m3a[r], fa ? 1.0f : 0.0f);
      cnt_a += fa ? (1u << (4 * r)) : 0u;
      m3b[r] = __fadd_rn(__fmul_rn(0.95f, m3b[r]), curb);
      bool fb = m3b[r] > 1.0f;
      m3b[r] = __fsub_rn(m3b[r], fb ? 1.0f : 0.0f);
      cnt_b += fb ? (1u << (4 * r)) : 0u;
    }
  }

  // ---- mean spikes (count/8 exact) into LDS
#pragma unroll
  for (int r = 0; r < RPT; ++r) {
    sl[(rbase + r) * HID + j1]       = (float)((cnt_a >> (4 * r)) & 15u) * 0.125f;
    sl[(rbase + r) * HID + j1 + 256] = (float)((cnt_b >> (4 * r)) & 15u) * 0.125f;
  }
  __syncthreads();

  // ---- heads (BLAS panel structure)
  if (is_value == 0) {
    if (tid < ROWS * 6) {
      int r = tid / 6, k = tid % 6;
      const float* wr = Wh + (size_t)k * HID;
      float S0 = 0.f, S1 = 0.f;
      for (int i = 0; i < 4 * KC4; ++i)   S0 = fmaf(sl[r * HID + i], wr[i], S0);
      for (int i = 4 * KC4; i < HID; ++i) S1 = fmaf(sl[r * HID + i], wr[i], S1);
      out[(size_t)(r0 + r) * 6 + k] = __fadd_rn(__fadd_rn(S0, S1), bh[k]);
      out[(size_t)B * 6 + (size_t)(r0 + r) * 6 + k] = log_std[k];
    }
  } else {
    if (tid < ROWS) {
      int r = tid;
      float S0 = 0.f, S1 = 0.f;
      for (int i = 0; i < 4 * KC4; ++i)   S0 = fmaf(sl[r * HID + i], Wh[i], S0);
      for (int i = 4 * KC4; i < HID; ++i) S1 = fmaf(sl[r * HID + i], Wh[i], S1);
      out[(size_t)B * 12 + (size_t)(r0 + r)] = __fadd_rn(__fadd_rn(S0, S1), bh[0]);
    }
  }
}

// ---------------- fallback (round-3 kernel, used if ws too small) ----------------
template<int PITCH4>
__device__ __forceinline__ void gemm_f32(const float* __restrict__ sl, int rbase,
                                         const float4* __restrict__ wra,
                                         const float4* __restrict__ wrb,
                                         int i4begin, int i4end,
                                         float a0[RPT], float a1[RPT]) {
  const float4* slv = reinterpret_cast<const float4*>(sl);
  for (int i4 = i4begin; i4 < i4end; ++i4) {
    float4 wa = wra[i4];
    float4 wb = wrb[i4];
#pragma unroll
    for (int r = 0; r < RPT; ++r) {
      float4 s = slv[(rbase + r) * PITCH4 + i4];
      a0[r] = fmaf(s.w, wa.w, fmaf(s.z, wa.z, fmaf(s.y, wa.y, fmaf(s.x, wa.x, a0[r]))));
      a1[r] = fmaf(s.w, wb.w, fmaf(s.z, wb.z, fmaf(s.y, wb.y, fmaf(s.x, wb.x, a1[r]))));
    }
  }
}

__launch_bounds__(NTHR, 2)
__global__ void snn_net_base(const float* __restrict__ obs,
                             const float* __restrict__ pW1, const float* __restrict__ pb1_,
                             const float* __restrict__ pW2, const float* __restrict__ pb2_,
                             const float* __restrict__ pW3, const float* __restrict__ pb3_,
                             const float* __restrict__ paw, const float* __restrict__ pab,
                             const float* __restrict__ vW1, const float* __restrict__ vb1_,
                             const float* __restrict__ vW2, const float* __restrict__ vb2_,
                             const float* __restrict__ vW3, const float* __restrict__ vb3_,
                             const float* __restrict__ vhw, const float* __restrict__ vhb,
                             const float* __restrict__ log_std,
                             float* __restrict__ out, int B) {
  const int is_value = blockIdx.y;
  const float* W1 = is_value ? vW1 : pW1;  const float* b1 = is_value ? vb1_ : pb1_;
  const float* W2 = is_value ? vW2 : pW2;  const float* b2 = is_value ? vb2_ : pb2_;
  const float* W3 = is_value ? vW3 : pW3;  const float* b3 = is_value ? vb3_ : pb3_;
  const float* Wh = is_value ? vhw : paw;  const float* bh = is_value ? vhb : pab;

  __shared__ float sl[ROWS * HID];
  const int tid = threadIdx.x;
  const int r0 = blockIdx.x * ROWS;
  const int j1 = tid & 255, j2 = j1 + 256;
  const int rbase = (tid >> 8) * RPT;

  for (int e = tid; e < ROWS * IN_DIM; e += NTHR)
    sl[e] = obs[(size_t)r0 * IN_DIM + e];
  __syncthreads();

  float c1a[RPT], c1b[RPT];
  {
    float Sa[RPT], Sb[RPT];
#pragma unroll
    for (int r = 0; r < RPT; ++r) { Sa[r] = 0.f; Sb[r] = 0.f; }
    gemm_f32<IN_DIM / 4>(sl, rbase,
        reinterpret_cast<const float4*>(W1 + (size_t)j1 * IN_DIM),
        reinterpret_cast<const float4*>(W1 + (size_t)j2 * IN_DIM),
        0, IN_DIM / 4, Sa, Sb);
    const float ba = b1[j1], bb = b1[j2];
#pragma unroll
    for (int r = 0; r < RPT; ++r) {
      c1a[r] = __fadd_rn(Sa[r], ba);
      c1b[r] = __fadd_rn(Sb[r], bb);
    }
  }
  __syncthreads();

  float m1a[RPT], m1b[RPT], m2a[RPT], m2b[RPT], m3a[RPT], m3b[RPT];
  float sca[RPT], scb[RPT];
#pragma unroll
  for (int r = 0; r < RPT; ++r) {
    m1a[r] = 0.f; m1b[r] = 0.f; m2a[r] = 0.f; m2b[r] = 0.f;
    m3a[r] = 0.f; m3b[r] = 0.f; sca[r] = 0.f; scb[r] = 0.f;
  }

  const float4* w2a = reinterpret_cast<const float4*>(W2 + (size_t)j1 * HID);
  const float4* w2b = reinterpret_cast<const float4*>(W2 + (size_t)j2 * HID);
  const float4* w3a = reinterpret_cast<const float4*>(W3 + (size_t)j1 * HID);
  const float4* w3b = reinterpret_cast<const float4*>(W3 + (size_t)j2 * HID);
  const float bias2a = b2[j1], bias2b = b2[j2];
  const float bias3a = b3[j1], bias3b = b3[j2];

  for (int t = 0; t < TSTEPS; ++t) {
#pragma unroll
    for (int r = 0; r < RPT; ++r) {
      m1a[r] = __fadd_rn(__fmul_rn(0.95f, m1a[r]), c1a[r]);
      float sa = (m1a[r] > 1.0f) ? 1.0f : 0.0f;
      m1a[r] = __fsub_rn(m1a[r], sa);
      sl[(rbase + r) * HID + j1] = sa;
      m1b[r] = __fadd_rn(__fmul_rn(0.95f, m1b[r]), c1b[r]);
      float sb = (m1b[r] > 1.0f) ? 1.0f : 0.0f;
      m1b[r] = __fsub_rn(m1b[r], sb);
      sl[(rbase + r) * HID + j2] = sb;
    }
    __syncthreads();

    float S0a[RPT], S0b[RPT], S1a[RPT], S1b[RPT];
#pragma unroll
    for (int r = 0; r < RPT; ++r) { S0a[r] = 0.f; S0b[r] = 0.f; S1a[r] = 0.f; S1b[r] = 0.f; }
    gemm_f32<HID / 4>(sl, rbase, w2a, w2b, 0, KC4, S0a, S0b);
    gemm_f32<HID / 4>(sl, rbase, w2a, w2b, KC4, HID / 4, S1a, S1b);
    __syncthreads();
#pragma unroll
    for (int r = 0; r < RPT; ++r) {
      float cura = __fadd_rn(__fadd_rn(S0a[r], S1a[r]), bias2a);
      float curb = __fadd_rn(__fadd_rn(S0b[r], S1b[r]), bias2b);
      m2a[r] = __fadd_rn(__fmul_rn(0.95f, m2a[r]), cura);
      float sa = (m2a[r] > 1.0f) ? 1.0f : 0.0f;
      m2a[r] = __fsub_rn(m2a[r], sa);
      sl[(rbase + r) * HID + j1] = sa;
      m2b[r] = __fadd_rn(__fmul_rn(0.95f, m2b[r]), curb);
      float sb = (m2b[r] > 1.0f) ? 1.0f : 0.0f;
      m2b[r] = __fsub_rn(m2b[r], sb);
      sl[(rbase + r) * HID + j2] = sb;
    }
    __syncthreads();

#pragma unroll
    for (int r = 0; r < RPT; ++r) { S0a[r] = 0.f; S0b[r] = 0.f; S1a[r] = 0.f; S1b[r] = 0.f; }
    gemm_f32<HID / 4>(sl, rbase, w3a, w3b, 0, KC4, S0a, S0b);
    gemm_f32<HID / 4>(sl, rbase, w3a, w3b, KC4, HID / 4, S1a, S1b);
    __syncthreads();
#pragma unroll
    for (int r = 0; r < RPT; ++r) {
      float cura = __fadd_rn(__fadd_rn(S0a[r], S1a[r]), bias3a);
      float curb = __fadd_rn(__fadd_rn(S0b[r], S1b[r]), bias3b);
      m3a[r] = __fadd_rn(__fmul_rn(0.95f, m3a[r]), cura);
      float sa = (m3a[r] > 1.0f) ? 1.0f : 0.0f;
      m3a[r] = __fsub_rn(m3a[r], sa);
      sca[r] = __fadd_rn(sca[r], sa);
      m3b[r] = __fadd_rn(__fmul_rn(0.95f, m3b[r]), curb);
      float sb = (m3b[r] > 1.0f) ? 1.0f : 0.0f;
      m3b[r] = __fsub_rn(m3b[r], sb);
      scb[r] = __fadd_rn(scb[r], sb);
    }
  }

#pragma unroll
  for (int r = 0; r < RPT; ++r) {
    sl[(rbase + r) * HID + j1] = sca[r] * 0.125f;
    sl[(rbase + r) * HID + j2] = scb[r] * 0.125f;
  }
  __syncthreads();

  if (is_value == 0) {
    if (tid < ROWS * 6) {
      int r = tid / 6, k = tid % 6;
      const float* wr = Wh + (size_t)k * HID;
      float S0 = 0.f, S1 = 0.f;
      for (int i = 0; i < 4 * KC4; ++i)   S0 = fmaf(sl[r * HID + i], wr[i], S0);
      for (int i = 4 * KC4; i < HID; ++i) S1 = fmaf(sl[r * HID + i], wr[i], S1);
      out[(size_t)(r0 + r) * 6 + k] = __fadd_rn(__fadd_rn(S0, S1), bh[k]);
      out[(size_t)B * 6 + (size_t)(r0 + r) * 6 + k] = log_std[k];
    }
  } else {
    if (tid < ROWS) {
      int r = tid;
      float S0 = 0.f, S1 = 0.f;
      for (int i = 0; i < 4 * KC4; ++i)   S0 = fmaf(sl[r * HID + i], Wh[i], S0);
      for (int i = 4 * KC4; i < HID; ++i) S1 = fmaf(sl[r * HID + i], Wh[i], S1);
      out[(size_t)B * 12 + (size_t)(r0 + r)] = __fadd_rn(__fadd_rn(S0, S1), bh[0]);
    }
  }
}

extern "C" void kernel_launch(void* const* d_in, const int* in_sizes, int n_in,
                              void* d_out, int out_size, void* d_ws, size_t ws_size,
                              hipStream_t stream) {
  const float* obs = (const float*)d_in[0];
  const float* pw1 = (const float*)d_in[1];  const float* pb1 = (const float*)d_in[2];
  const float* pw2 = (const float*)d_in[3];  const float* pb2 = (const float*)d_in[4];
  const float* pw3 = (const float*)d_in[5];  const float* pb3 = (const float*)d_in[6];
  const float* aw  = (const float*)d_in[7];  const float* ab  = (const float*)d_in[8];
  const float* vw1 = (const float*)d_in[9];  const float* vb1 = (const float*)d_in[10];
  const float* vw2 = (const float*)d_in[11]; const float* vb2 = (const float*)d_in[12];
  const float* vw3 = (const float*)d_in[13]; const float* vb3 = (const float*)d_in[14];
  const float* hw  = (const float*)d_in[15]; const float* hb  = (const float*)d_in[16];
  const float* lsd = (const float*)d_in[17];
  float* out = (float*)d_out;

  const int B = in_sizes[0] / IN_DIM;
  dim3 grid(B / ROWS, 2);

  const size_t need = (size_t)(IN_DIM * HID + 2 * HID * HID) * 2 * sizeof(float);
  if (ws_size >= need) {
    float* w = (float*)d_ws;
    float* pW1T = w;                 // [256][512]
    float* pW2T = w + 131072;        // [512][512]
    float* pW3T = w + 393216;
    float* vW1T = w + 655360;
    float* vW2T = w + 786432;
    float* vW3T = w + 1048576;
    wtrans<<<dim3(IN_DIM / 32, HID / 32), 256, 0, stream>>>(pw1, pW1T, HID, IN_DIM);
    wtrans<<<dim3(HID / 32, HID / 32), 256, 0, stream>>>(pw2, pW2T, HID, HID);
    wtrans<<<dim3(HID / 32, HID / 32), 256, 0, stream>>>(pw3, pW3T, HID, HID);
    wtrans<<<dim3(IN_DIM / 32, HID / 32), 256, 0, stream>>>(vw1, vW1T, HID, IN_DIM);
    wtrans<<<dim3(HID / 32, HID / 32), 256, 0, stream>>>(vw2, vW2T, HID, HID);
    wtrans<<<dim3(HID / 32, HID / 32), 256, 0, stream>>>(vw3, vW3T, HID, HID);
    snn_net<<<grid, NTHR, 0, stream>>>(obs,
        pW1T, pb1, pW2T, pb2, pW3T, pb3, aw, ab,
        vW1T, vb1, vW2T, vb2, vW3T, vb3, hw, hb,
        lsd, out, B);
  } else {
    snn_net_base<<<grid, NTHR, 0, stream>>>(obs,
        pw1, pb1, pw2, pb2, pw3, pb3, aw, ab,
        vw1, vb1, vw2, vb2, vw3, vb3, hw, hb,
        lsd, out, B);
  }
}

// Round 5
// 4121.046 us; speedup vs baseline: 3.3648x; 1.1824x over previous
//
#include <hip/hip_runtime.h>
#include <cstdint>
#include <cstddef>

#define IN_DIM 256
#define HID    512
#define TSTEPS 8
#define ROWS   16      // batch rows per block
#define RPT    8       // rows per thread
#define NTHR   512
#define KC4    96      // OpenBLAS sgemm kc=384 panel boundary, in float4 units

// ---- weight pack: in[R rows][C cols] -> out4[k4*R + j] = {in[j][4k4..4k4+3]} ----
// (j = output column of the GEMM = weight row; k = reduction index)
__global__ void wpack(const float* __restrict__ in, float4* __restrict__ out4,
                      int R, int C) {
  __shared__ float tile[32][33];
  const int k0 = blockIdx.x * 32;   // k-block
  const int j0 = blockIdx.y * 32;   // j-block
  const int tx = threadIdx.x & 31, ty = threadIdx.x >> 5;  // 256 thr = 32x8
#pragma unroll
  for (int i = 0; i < 32; i += 8)
    tile[ty + i][tx] = in[(size_t)(j0 + ty + i) * C + (k0 + tx)];  // coalesced in k
  __syncthreads();
  const int k4i = threadIdx.x >> 5;   // 0..7
  const int jj  = threadIdx.x & 31;
  float4 v = make_float4(tile[jj][4 * k4i + 0], tile[jj][4 * k4i + 1],
                         tile[jj][4 * k4i + 2], tile[jj][4 * k4i + 3]);
  out4[(size_t)(k0 / 4 + k4i) * R + (j0 + jj)] = v;   // coalesced in j
}

// ---- packed-weight GEMM core: ascending-k fp32 fma chain (BLAS GEBP order,
// bit-identical to the round-3-verified rounding). Weights: 2 coalesced
// dwordx4/iter. Spikes: wave-uniform broadcast ds_read_b128 (conflict-free).
__device__ __forceinline__ void gemm_tp(const float* __restrict__ sl, int rbase,
                                        int pitch4,
                                        const float4* __restrict__ wpk, int j1,
                                        int i4begin, int i4end,
                                        float a0[RPT], float a1[RPT]) {
  const float4* slv = reinterpret_cast<const float4*>(sl);
  const float4* wp = wpk + (size_t)i4begin * HID + j1;
  for (int i4 = i4begin; i4 < i4end; ++i4) {
    float4 wa = wp[0];
    float4 wb = wp[256];
#pragma unroll
    for (int r = 0; r < RPT; ++r) {
      float4 s = slv[(rbase + r) * pitch4 + i4];
      a0[r] = fmaf(s.w, wa.w, fmaf(s.z, wa.z, fmaf(s.y, wa.y, fmaf(s.x, wa.x, a0[r]))));
      a1[r] = fmaf(s.w, wb.w, fmaf(s.z, wb.z, fmaf(s.y, wb.y, fmaf(s.x, wb.x, a1[r]))));
    }
    wp += HID;
  }
}

// launch_bounds 2nd arg is CUDA-style min-blocks/CU on this toolchain (measured:
// (512,2)->128 VGPR no spills, (512,4)->64 VGPR + 440MB scratch writes).
__launch_bounds__(NTHR, 2)
__global__ void snn_net(const float* __restrict__ obs,
                        const float4* __restrict__ pW1P, const float* __restrict__ pb1_,
                        const float4* __restrict__ pW2P, const float* __restrict__ pb2_,
                        const float4* __restrict__ pW3P, const float* __restrict__ pb3_,
                        const float* __restrict__ paw, const float* __restrict__ pab,
                        const float4* __restrict__ vW1P, const float* __restrict__ vb1_,
                        const float4* __restrict__ vW2P, const float* __restrict__ vb2_,
                        const float4* __restrict__ vW3P, const float* __restrict__ vb3_,
                        const float* __restrict__ vhw, const float* __restrict__ vhb,
                        const float* __restrict__ log_std,
                        float* __restrict__ out, int B) {
  // XCD-aware split: consecutive blockIdx round-robins XCDs; put policy on
  // XCD 0-3, value on XCD 4-7 so each L2 holds one net's 2.6MB packed weights.
  const int bid = blockIdx.x;
  const int xcd = bid & 7;
  const int is_value = xcd >> 2;
  const int tile = (bid >> 3) * 4 + (xcd & 3);
  const float4* W1P = is_value ? vW1P : pW1P;  const float* b1 = is_value ? vb1_ : pb1_;
  const float4* W2P = is_value ? vW2P : pW2P;  const float* b2 = is_value ? vb2_ : pb2_;
  const float4* W3P = is_value ? vW3P : pW3P;  const float* b3 = is_value ? vb3_ : pb3_;
  const float* Wh   = is_value ? vhw  : paw;   const float* bh = is_value ? vhb : pab;

  __shared__ float sl[ROWS * HID];  // 32 KB: obs tile then spike tile
  const int tid = threadIdx.x;
  const int r0 = tile * ROWS;
  const int j1 = tid & 255;
  const int rbase = (tid >> 8) * RPT;   // 0 or 8

  // ---- stage obs tile
  for (int e = tid; e < ROWS * IN_DIM; e += NTHR)
    sl[e] = obs[(size_t)r0 * IN_DIM + e];
  __syncthreads();

  // ---- layer-1 currents: K=256 single panel; bias added AFTER sum
  float c1a[RPT], c1b[RPT];
  {
    float Sa[RPT], Sb[RPT];
#pragma unroll
    for (int r = 0; r < RPT; ++r) { Sa[r] = 0.f; Sb[r] = 0.f; }
    gemm_tp(sl, rbase, IN_DIM / 4, W1P, j1, 0, IN_DIM / 4, Sa, Sb);
    const float ba = b1[j1], bb = b1[j1 + 256];
#pragma unroll
    for (int r = 0; r < RPT; ++r) {
      c1a[r] = __fadd_rn(Sa[r], ba);
      c1b[r] = __fadd_rn(Sb[r], bb);
    }
  }
  __syncthreads();  // obs tile dead; sl becomes spike tile

  // ---- fp32 membrane state; layer-3 spike counts packed 4b x 8 per u32
  float m1a[RPT], m1b[RPT], m2a[RPT], m2b[RPT], m3a[RPT], m3b[RPT];
  unsigned cnt_a = 0u, cnt_b = 0u;
#pragma unroll
  for (int r = 0; r < RPT; ++r) {
    m1a[r] = 0.f; m1b[r] = 0.f; m2a[r] = 0.f; m2b[r] = 0.f;
    m3a[r] = 0.f; m3b[r] = 0.f;
  }

  const float bias2a = b2[j1], bias2b = b2[j1 + 256];
  const float bias3a = b3[j1], bias3b = b3[j1 + 256];

  for (int t = 0; t < TSTEPS; ++t) {
    // LIF layer 1: m = RN(RN(0.95*m) + cur)  (numpy: mul then add, no fma)
#pragma unroll
    for (int r = 0; r < RPT; ++r) {
      m1a[r] = __fadd_rn(__fmul_rn(0.95f, m1a[r]), c1a[r]);
      float sa = (m1a[r] > 1.0f) ? 1.0f : 0.0f;
      m1a[r] = __fsub_rn(m1a[r], sa);
      sl[(rbase + r) * HID + j1] = sa;
      m1b[r] = __fadd_rn(__fmul_rn(0.95f, m1b[r]), c1b[r]);
      float sb = (m1b[r] > 1.0f) ? 1.0f : 0.0f;
      m1b[r] = __fsub_rn(m1b[r], sb);
      sl[(rbase + r) * HID + j1 + 256] = sb;
    }
    __syncthreads();

    // layer 2: two BLAS panels (kc=384), RN(S0+S1), then +bias
    float S0a[RPT], S0b[RPT], S1a[RPT], S1b[RPT];
#pragma unroll
    for (int r = 0; r < RPT; ++r) { S0a[r] = 0.f; S0b[r] = 0.f; S1a[r] = 0.f; S1b[r] = 0.f; }
    gemm_tp(sl, rbase, HID / 4, W2P, j1, 0, KC4, S0a, S0b);
    gemm_tp(sl, rbase, HID / 4, W2P, j1, KC4, HID / 4, S1a, S1b);
    __syncthreads();  // s1 reads done before overwrite
#pragma unroll
    for (int r = 0; r < RPT; ++r) {
      float cura = __fadd_rn(__fadd_rn(S0a[r], S1a[r]), bias2a);
      float curb = __fadd_rn(__fadd_rn(S0b[r], S1b[r]), bias2b);
      m2a[r] = __fadd_rn(__fmul_rn(0.95f, m2a[r]), cura);
      float sa = (m2a[r] > 1.0f) ? 1.0f : 0.0f;
      m2a[r] = __fsub_rn(m2a[r], sa);
      sl[(rbase + r) * HID + j1] = sa;
      m2b[r] = __fadd_rn(__fmul_rn(0.95f, m2b[r]), curb);
      float sb = (m2b[r] > 1.0f) ? 1.0f : 0.0f;
      m2b[r] = __fsub_rn(m2b[r], sb);
      sl[(rbase + r) * HID + j1 + 256] = sb;
    }
    __syncthreads();

    // layer 3: same two-panel structure; packed spike counts
#pragma unroll
    for (int r = 0; r < RPT; ++r) { S0a[r] = 0.f; S0b[r] = 0.f; S1a[r] = 0.f; S1b[r] = 0.f; }
    gemm_tp(sl, rbase, HID / 4, W3P, j1, 0, KC4, S0a, S0b);
    gemm_tp(sl, rbase, HID / 4, W3P, j1, KC4, HID / 4, S1a, S1b);
    __syncthreads();  // s2 reads done before next step overwrites
#pragma unroll
    for (int r = 0; r < RPT; ++r) {
      float cura = __fadd_rn(__fadd_rn(S0a[r], S1a[r]), bias3a);
      float curb = __fadd_rn(__fadd_rn(S0b[r], S1b[r]), bias3b);
      m3a[r] = __fadd_rn(__fmul_rn(0.95f, m3a[r]), cura);
      bool fa = m3a[r] > 1.0f;
      m3a[r] = __fsub_rn(m3a[r], fa ? 1.0f : 0.0f);
      cnt_a += fa ? (1u << (4 * r)) : 0u;
      m3b[r] = __fadd_rn(__fmul_rn(0.95f, m3b[r]), curb);
      bool fb = m3b[r] > 1.0f;
      m3b[r] = __fsub_rn(m3b[r], fb ? 1.0f : 0.0f);
      cnt_b += fb ? (1u << (4 * r)) : 0u;
    }
  }

  // ---- mean spikes (count/8 exact) into LDS
#pragma unroll
  for (int r = 0; r < RPT; ++r) {
    sl[(rbase + r) * HID + j1]       = (float)((cnt_a >> (4 * r)) & 15u) * 0.125f;
    sl[(rbase + r) * HID + j1 + 256] = (float)((cnt_b >> (4 * r)) & 15u) * 0.125f;
  }
  __syncthreads();

  // ---- heads (BLAS panel structure)
  if (is_value == 0) {
    if (tid < ROWS * 6) {
      int r = tid / 6, k = tid % 6;
      const float* wr = Wh + (size_t)k * HID;
      float S0 = 0.f, S1 = 0.f;
      for (int i = 0; i < 4 * KC4; ++i)   S0 = fmaf(sl[r * HID + i], wr[i], S0);
      for (int i = 4 * KC4; i < HID; ++i) S1 = fmaf(sl[r * HID + i], wr[i], S1);
      out[(size_t)(r0 + r) * 6 + k] = __fadd_rn(__fadd_rn(S0, S1), bh[k]);
      out[(size_t)B * 6 + (size_t)(r0 + r) * 6 + k] = log_std[k];
    }
  } else {
    if (tid < ROWS) {
      int r = tid;
      float S0 = 0.f, S1 = 0.f;
      for (int i = 0; i < 4 * KC4; ++i)   S0 = fmaf(sl[r * HID + i], Wh[i], S0);
      for (int i = 4 * KC4; i < HID; ++i) S1 = fmaf(sl[r * HID + i], Wh[i], S1);
      out[(size_t)B * 12 + (size_t)(r0 + r)] = __fadd_rn(__fadd_rn(S0, S1), bh[0]);
    }
  }
}

// ---------------- fallback (round-3 kernel, used if ws too small / odd shapes) ----
template<int PITCH4>
__device__ __forceinline__ void gemm_f32(const float* __restrict__ sl, int rbase,
                                         const float4* __restrict__ wra,
                                         const float4* __restrict__ wrb,
                                         int i4begin, int i4end,
                                         float a0[RPT], float a1[RPT]) {
  const float4* slv = reinterpret_cast<const float4*>(sl);
  for (int i4 = i4begin; i4 < i4end; ++i4) {
    float4 wa = wra[i4];
    float4 wb = wrb[i4];
#pragma unroll
    for (int r = 0; r < RPT; ++r) {
      float4 s = slv[(rbase + r) * PITCH4 + i4];
      a0[r] = fmaf(s.w, wa.w, fmaf(s.z, wa.z, fmaf(s.y, wa.y, fmaf(s.x, wa.x, a0[r]))));
      a1[r] = fmaf(s.w, wb.w, fmaf(s.z, wb.z, fmaf(s.y, wb.y, fmaf(s.x, wb.x, a1[r]))));
    }
  }
}

__launch_bounds__(NTHR, 2)
__global__ void snn_net_base(const float* __restrict__ obs,
                             const float* __restrict__ pW1, const float* __restrict__ pb1_,
                             const float* __restrict__ pW2, const float* __restrict__ pb2_,
                             const float* __restrict__ pW3, const float* __restrict__ pb3_,
                             const float* __restrict__ paw, const float* __restrict__ pab,
                             const float* __restrict__ vW1, const float* __restrict__ vb1_,
                             const float* __restrict__ vW2, const float* __restrict__ vb2_,
                             const float* __restrict__ vW3, const float* __restrict__ vb3_,
                             const float* __restrict__ vhw, const float* __restrict__ vhb,
                             const float* __restrict__ log_std,
                             float* __restrict__ out, int B) {
  const int is_value = blockIdx.y;
  const float* W1 = is_value ? vW1 : pW1;  const float* b1 = is_value ? vb1_ : pb1_;
  const float* W2 = is_value ? vW2 : pW2;  const float* b2 = is_value ? vb2_ : pb2_;
  const float* W3 = is_value ? vW3 : pW3;  const float* b3 = is_value ? vb3_ : pb3_;
  const float* Wh = is_value ? vhw : paw;  const float* bh = is_value ? vhb : pab;

  __shared__ float sl[ROWS * HID];
  const int tid = threadIdx.x;
  const int r0 = blockIdx.x * ROWS;
  const int j1 = tid & 255, j2 = j1 + 256;
  const int rbase = (tid >> 8) * RPT;

  for (int e = tid; e < ROWS * IN_DIM; e += NTHR)
    sl[e] = obs[(size_t)r0 * IN_DIM + e];
  __syncthreads();

  float c1a[RPT], c1b[RPT];
  {
    float Sa[RPT], Sb[RPT];
#pragma unroll
    for (int r = 0; r < RPT; ++r) { Sa[r] = 0.f; Sb[r] = 0.f; }
    gemm_f32<IN_DIM / 4>(sl, rbase,
        reinterpret_cast<const float4*>(W1 + (size_t)j1 * IN_DIM),
        reinterpret_cast<const float4*>(W1 + (size_t)j2 * IN_DIM),
        0, IN_DIM / 4, Sa, Sb);
    const float ba = b1[j1], bb = b1[j2];
#pragma unroll
    for (int r = 0; r < RPT; ++r) {
      c1a[r] = __fadd_rn(Sa[r], ba);
      c1b[r] = __fadd_rn(Sb[r], bb);
    }
  }
  __syncthreads();

  float m1a[RPT], m1b[RPT], m2a[RPT], m2b[RPT], m3a[RPT], m3b[RPT];
  float sca[RPT], scb[RPT];
#pragma unroll
  for (int r = 0; r < RPT; ++r) {
    m1a[r] = 0.f; m1b[r] = 0.f; m2a[r] = 0.f; m2b[r] = 0.f;
    m3a[r] = 0.f; m3b[r] = 0.f; sca[r] = 0.f; scb[r] = 0.f;
  }

  const float4* w2a = reinterpret_cast<const float4*>(W2 + (size_t)j1 * HID);
  const float4* w2b = reinterpret_cast<const float4*>(W2 + (size_t)j2 * HID);
  const float4* w3a = reinterpret_cast<const float4*>(W3 + (size_t)j1 * HID);
  const float4* w3b = reinterpret_cast<const float4*>(W3 + (size_t)j2 * HID);
  const float bias2a = b2[j1], bias2b = b2[j2];
  const float bias3a = b3[j1], bias3b = b3[j2];

  for (int t = 0; t < TSTEPS; ++t) {
#pragma unroll
    for (int r = 0; r < RPT; ++r) {
      m1a[r] = __fadd_rn(__fmul_rn(0.95f, m1a[r]), c1a[r]);
      float sa = (m1a[r] > 1.0f) ? 1.0f : 0.0f;
      m1a[r] = __fsub_rn(m1a[r], sa);
      sl[(rbase + r) * HID + j1] = sa;
      m1b[r] = __fadd_rn(__fmul_rn(0.95f, m1b[r]), c1b[r]);
      float sb = (m1b[r] > 1.0f) ? 1.0f : 0.0f;
      m1b[r] = __fsub_rn(m1b[r], sb);
      sl[(rbase + r) * HID + j2] = sb;
    }
    __syncthreads();

    float S0a[RPT], S0b[RPT], S1a[RPT], S1b[RPT];
#pragma unroll
    for (int r = 0; r < RPT; ++r) { S0a[r] = 0.f; S0b[r] = 0.f; S1a[r] = 0.f; S1b[r] = 0.f; }
    gemm_f32<HID / 4>(sl, rbase, w2a, w2b, 0, KC4, S0a, S0b);
    gemm_f32<HID / 4>(sl, rbase, w2a, w2b, KC4, HID / 4, S1a, S1b);
    __syncthreads();
#pragma unroll
    for (int r = 0; r < RPT; ++r) {
      float cura = __fadd_rn(__fadd_rn(S0a[r], S1a[r]), bias2a);
      float curb = __fadd_rn(__fadd_rn(S0b[r], S1b[r]), bias2b);
      m2a[r] = __fadd_rn(__fmul_rn(0.95f, m2a[r]), cura);
      float sa = (m2a[r] > 1.0f) ? 1.0f : 0.0f;
      m2a[r] = __fsub_rn(m2a[r], sa);
      sl[(rbase + r) * HID + j1] = sa;
      m2b[r] = __fadd_rn(__fmul_rn(0.95f, m2b[r]), curb);
      float sb = (m2b[r] > 1.0f) ? 1.0f : 0.0f;
      m2b[r] = __fsub_rn(m2b[r], sb);
      sl[(rbase + r) * HID + j2] = sb;
    }
    __syncthreads();

#pragma unroll
    for (int r = 0; r < RPT; ++r) { S0a[r] = 0.f; S0b[r] = 0.f; S1a[r] = 0.f; S1b[r] = 0.f; }
    gemm_f32<HID / 4>(sl, rbase, w3a, w3b, 0, KC4, S0a, S0b);
    gemm_f32<HID / 4>(sl, rbase, w3a, w3b, KC4, HID / 4, S1a, S1b);
    __syncthreads();
#pragma unroll
    for (int r = 0; r < RPT; ++r) {
      float cura = __fadd_rn(__fadd_rn(S0a[r], S1a[r]), bias3a);
      float curb = __fadd_rn(__fadd_rn(S0b[r], S1b[r]), bias3b);
      m3a[r] = __fadd_rn(__fmul_rn(0.95f, m3a[r]), cura);
      float sa = (m3a[r] > 1.0f) ? 1.0f : 0.0f;
      m3a[r] = __fsub_rn(m3a[r], sa);
      sca[r] = __fadd_rn(sca[r], sa);
      m3b[r] = __fadd_rn(__fmul_rn(0.95f, m3b[r]), curb);
      float sb = (m3b[r] > 1.0f) ? 1.0f : 0.0f;
      m3b[r] = __fsub_rn(m3b[r], sb);
      scb[r] = __fadd_rn(scb[r], sb);
    }
  }

#pragma unroll
  for (int r = 0; r < RPT; ++r) {
    sl[(rbase + r) * HID + j1] = sca[r] * 0.125f;
    sl[(rbase + r) * HID + j2] = scb[r] * 0.125f;
  }
  __syncthreads();

  if (is_value == 0) {
    if (tid < ROWS * 6) {
      int r = tid / 6, k = tid % 6;
      const float* wr = Wh + (size_t)k * HID;
      float S0 = 0.f, S1 = 0.f;
      for (int i = 0; i < 4 * KC4; ++i)   S0 = fmaf(sl[r * HID + i], wr[i], S0);
      for (int i = 4 * KC4; i < HID; ++i) S1 = fmaf(sl[r * HID + i], wr[i], S1);
      out[(size_t)(r0 + r) * 6 + k] = __fadd_rn(__fadd_rn(S0, S1), bh[k]);
      out[(size_t)B * 6 + (size_t)(r0 + r) * 6 + k] = log_std[k];
    }
  } else {
    if (tid < ROWS) {
      int r = tid;
      float S0 = 0.f, S1 = 0.f;
      for (int i = 0; i < 4 * KC4; ++i)   S0 = fmaf(sl[r * HID + i], Wh[i], S0);
      for (int i = 4 * KC4; i < HID; ++i) S1 = fmaf(sl[r * HID + i], Wh[i], S1);
      out[(size_t)B * 12 + (size_t)(r0 + r)] = __fadd_rn(__fadd_rn(S0, S1), bh[0]);
    }
  }
}

extern "C" void kernel_launch(void* const* d_in, const int* in_sizes, int n_in,
                              void* d_out, int out_size, void* d_ws, size_t ws_size,
                              hipStream_t stream) {
  const float* obs = (const float*)d_in[0];
  const float* pw1 = (const float*)d_in[1];  const float* pb1 = (const float*)d_in[2];
  const float* pw2 = (const float*)d_in[3];  const float* pb2 = (const float*)d_in[4];
  const float* pw3 = (const float*)d_in[5];  const float* pb3 = (const float*)d_in[6];
  const float* aw  = (const float*)d_in[7];  const float* ab  = (const float*)d_in[8];
  const float* vw1 = (const float*)d_in[9];  const float* vb1 = (const float*)d_in[10];
  const float* vw2 = (const float*)d_in[11]; const float* vb2 = (const float*)d_in[12];
  const float* vw3 = (const float*)d_in[13]; const float* vb3 = (const float*)d_in[14];
  const float* hw  = (const float*)d_in[15]; const float* hb  = (const float*)d_in[16];
  const float* lsd = (const float*)d_in[17];
  float* out = (float*)d_out;

  const int B  = in_sizes[0] / IN_DIM;
  const int nb = B / ROWS;

  const size_t need = (size_t)(IN_DIM * HID + 2 * HID * HID) * 2 * sizeof(float);
  if (ws_size >= need && (nb & 3) == 0) {
    float* w = (float*)d_ws;
    float4* pW1P = (float4*)(w);              // [64][512]  float4
    float4* pW2P = (float4*)(w + 131072);     // [128][512] float4
    float4* pW3P = (float4*)(w + 393216);
    float4* vW1P = (float4*)(w + 655360);
    float4* vW2P = (float4*)(w + 786432);
    float4* vW3P = (float4*)(w + 1048576);
    wpack<<<dim3(IN_DIM / 32, HID / 32), 256, 0, stream>>>(pw1, pW1P, HID, IN_DIM);
    wpack<<<dim3(HID / 32, HID / 32), 256, 0, stream>>>(pw2, pW2P, HID, HID);
    wpack<<<dim3(HID / 32, HID / 32), 256, 0, stream>>>(pw3, pW3P, HID, HID);
    wpack<<<dim3(IN_DIM / 32, HID / 32), 256, 0, stream>>>(vw1, vW1P, HID, IN_DIM);
    wpack<<<dim3(HID / 32, HID / 32), 256, 0, stream>>>(vw2, vW2P, HID, HID);
    wpack<<<dim3(HID / 32, HID / 32), 256, 0, stream>>>(vw3, vW3P, HID, HID);
    snn_net<<<2 * nb, NTHR, 0, stream>>>(obs,
        pW1P, pb1, pW2P, pb2, pW3P, pb3, aw, ab,
        vW1P, vb1, vW2P, vb2, vW3P, vb3, hw, hb,
        lsd, out, B);
  } else {
    dim3 grid(nb, 2);
    snn_net_base<<<grid, NTHR, 0, stream>>>(obs,
        pw1, pb1, pw2, pb2, pw3, pb3, aw, ab,
        vw1, vb1, vw2, vb2, vw3, vb3, hw, hb,
        lsd, out, B);
  }
}